// Round 8
// baseline (115.319 us; speedup 1.0000x reference)
//
#include <hip/hip_runtime.h>

// DotProductAttention reduced form (verified rounds 1-8, absmax 0.0156):
//   Qeff[q] = 0.7*Q[q-1] + Q[q] + 0.7*Q[q+1]  (zero pad at edges)
//   out[q]  = softmax_{k <= max(q-1,0)}( Qeff[q]·K[k]/8 + beta[k] ) @ V
// Round 17: r16 (macro rewrite, grid 256) proved frag state must live in plain
// locals (lambda-by-ref escape -> scratch was the cross-round anomaly); first
// improvement (116.4 -> 113.9, attn ~34us). But grid 256 = 1 block/CU = 2
// waves/SIMD -- the occupancy wall r12 identified. This round: macros + the
// r14 decomposition (its 54us was the lambda scratch, not the structure):
// grid 512 = head x one 64-row q-tile (odd/even j map, co-resident pairs sum
// to 33 tiles), 8 waves (kh x par x qh), 2 blocks/CU = 4 waves/SIMD.
// Register demand ~120 <= 128 budget pinned by __launch_bounds__(512,4):
// SINGLE ka buffer, prefetch ka(tile+2) in-comp right after the S-MFMAs
// consume it (~300cy to next use, covers L2); vb loaded at comp start
// (consumed after softmax); beta exp-scaled in LDS. Epilogue: r14's verified
// 3-barrier 4-way (kh x par) combine. cvt8 unchanged.

typedef short bf16x8 __attribute__((ext_vector_type(8)));
typedef float f32x4  __attribute__((ext_vector_type(4)));

constexpr int S_ = 2048;
constexpr int D_ = 64;
constexpr float LOG2E = 1.44269504088896341f;
constexpr float KSC = 0.125f * LOG2E;   // 1/sqrt(64), log2 domain

// pack two fp32 -> dword of 2 bf16 (round-half-up), lo in low 16
__device__ __forceinline__ unsigned pk2(float lo, float hi) {
    union { float f; unsigned u; } a, b;
    a.f = lo; b.f = hi;
    return __builtin_amdgcn_perm(b.u + 0x8000u, a.u + 0x8000u, 0x07060302u);
}

// ---- fragment pre-swizzle: F[hd][tile][frag][lane][8] bf16 ----
// frag 0..7  = K A-frags  (kh*4 + mb*2 + hh): lane(n,qd) holds
//              K[key = 64t + 32kh + 8(n>>2) + (n&3) + 4mb][d = 32hh + 8qd .. +8]
// frag 8..15 = V^T A-frags (8 + kh*4 + mb): lane(n,qd) holds
//              V[key = 64t + 32kh + 8qd + j][d = 16mb + n], j = 0..7
__global__ __launch_bounds__(256)
void cvt8(const float* __restrict__ K, const float* __restrict__ V,
          unsigned short* __restrict__ F)
{
    __shared__ float T[64][68];   // V^T fp32: [d][key]

    const int bid = blockIdx.x;            // 512: hd = bid&15 -> XCD bid%8 (matches attn)
    const int hd = bid & 15, tt = bid >> 4;
    const float* Kt = K + ((size_t)hd * S_ + tt * 64) * D_;
    const float* Vt = V + ((size_t)hd * S_ + tt * 64) * D_;
    unsigned short* Ft = F + (size_t)(hd * 32 + tt) * 8192;

    const int t = threadIdx.x;
    const int key = t >> 2, d0 = (t & 3) << 4;

    // ---- V: coalesced read -> transposed LDS ----
    {
        const float* vp = Vt + key * D_ + d0;
        #pragma unroll
        for (int i = 0; i < 4; ++i) {
            float4 v4 = *(const float4*)(vp + 4 * i);
            T[d0 + 4 * i + 0][key] = v4.x;
            T[d0 + 4 * i + 1][key] = v4.y;
            T[d0 + 4 * i + 2][key] = v4.z;
            T[d0 + 4 * i + 3][key] = v4.w;
        }
    }

    // ---- K: coalesced read -> direct frag write ----
    {
        const float* kp = Kt + key * D_ + d0;
        float4 a = *(const float4*)(kp);
        float4 b = *(const float4*)(kp + 4);
        float4 c = *(const float4*)(kp + 8);
        float4 d = *(const float4*)(kp + 12);
        uint4 w0 = make_uint4(pk2(a.x, a.y), pk2(a.z, a.w), pk2(b.x, b.y), pk2(b.z, b.w));
        uint4 w1 = make_uint4(pk2(c.x, c.y), pk2(c.z, c.w), pk2(d.x, d.y), pk2(d.z, d.w));
        const int r5 = key & 31;
        const int kh = key >> 5, mb = (r5 >> 2) & 1;
        const int n = ((r5 >> 3) << 2) | (r5 & 3);       // inverse key->M-row perm
        const int hh = d0 >> 5, qd0 = (d0 >> 3) & 3;
        const int f0 = (kh << 2) | (mb << 1) | hh;
        *(uint4*)(Ft + f0 * 512 + ((qd0 << 4) | n) * 8)       = w0;
        *(uint4*)(Ft + f0 * 512 + (((qd0 + 1) << 4) | n) * 8) = w1;
    }
    __syncthreads();

    // ---- V frag emission: contiguous LDS reads, coalesced 16B writes ----
    #pragma unroll
    for (int s = 0; s < 2; ++s) {
        const int slot = t + s * 256;
        const int fr = slot >> 6, lane = slot & 63;
        const int kh = fr >> 2, mb = fr & 3, n = lane & 15, qd = lane >> 4;
        const float* row = &T[mb * 16 + n][kh * 32 + qd * 8];
        uint4 w = make_uint4(pk2(row[0], row[1]), pk2(row[2], row[3]),
                             pk2(row[4], row[5]), pk2(row[6], row[7]));
        *(uint4*)(Ft + (8 + fr) * 512 + lane * 8) = w;
    }
}

// ---- macro (not lambda!) tile load/compute: plain-local access, no escape ----
#define LD_KA(TILE, KA) do {                                                 \
    const unsigned short* fq_ = Fh + (size_t)(TILE) * 8192;                  \
    KA[0][0] = *(const bf16x8*)(fq_ + kfo[0][0]);                            \
    KA[0][1] = *(const bf16x8*)(fq_ + kfo[0][1]);                            \
    KA[1][0] = *(const bf16x8*)(fq_ + kfo[1][0]);                            \
    KA[1][1] = *(const bf16x8*)(fq_ + kfo[1][1]);                            \
} while (0)

#define COMP_T(TILE, KA, PRE) do {                                           \
    const int kb_ = ((TILE) << 6) + kvo;                                     \
    const unsigned short* fp_ = Fh + (size_t)(TILE) * 8192;                  \
    const bf16x8 vb0_ = *(const bf16x8*)(fp_ + vfo[0]);                      \
    const bf16x8 vb1_ = *(const bf16x8*)(fp_ + vfo[1]);                      \
    const bf16x8 vb2_ = *(const bf16x8*)(fp_ + vfo[2]);                      \
    const bf16x8 vb3_ = *(const bf16x8*)(fp_ + vfo[3]);                      \
    const float4 b0_ = *(const float4*)&bl[kb_];                             \
    const float4 b1_ = *(const float4*)&bl[kb_ + 4];                         \
    const float bt_[8] = {b0_.x, b0_.y, b0_.z, b0_.w,                        \
                          b1_.x, b1_.y, b1_.z, b1_.w};                       \
    const f32x4 zz_ = {0, 0, 0, 0};                                          \
    f32x4 acc_[2][2];                                                        \
    acc_[0][0] = __builtin_amdgcn_mfma_f32_16x16x32_bf16(KA[0][1], qb[0][1], \
        __builtin_amdgcn_mfma_f32_16x16x32_bf16(KA[0][0], qb[0][0], zz_, 0, 0, 0), 0, 0, 0); \
    acc_[0][1] = __builtin_amdgcn_mfma_f32_16x16x32_bf16(KA[0][1], qb[1][1], \
        __builtin_amdgcn_mfma_f32_16x16x32_bf16(KA[0][0], qb[1][0], zz_, 0, 0, 0), 0, 0, 0); \
    acc_[1][0] = __builtin_amdgcn_mfma_f32_16x16x32_bf16(KA[1][1], qb[0][1], \
        __builtin_amdgcn_mfma_f32_16x16x32_bf16(KA[1][0], qb[0][0], zz_, 0, 0, 0), 0, 0, 0); \
    acc_[1][1] = __builtin_amdgcn_mfma_f32_16x16x32_bf16(KA[1][1], qb[1][1], \
        __builtin_amdgcn_mfma_f32_16x16x32_bf16(KA[1][0], qb[1][0], zz_, 0, 0, 0), 0, 0, 0); \
    PRE;                                                                     \
    const bool dm_ = (TILE) == nt - 1;                                       \
    _Pragma("unroll")                                                        \
    for (int ng_ = 0; ng_ < 2; ++ng_) {                                      \
        const int qr_ = qbase + (ng_ << 4) + n_l;                            \
        float pv_[8];                                                        \
        float la_ = 0.0f;                                                    \
        _Pragma("unroll")                                                    \
        for (int jj_ = 0; jj_ < 8; ++jj_) {                                  \
            float sv_ = fmaf(acc_[jj_ >> 2][ng_][jj_ & 3], KSC, bt_[jj_]);   \
            if (dm_) {                                                       \
                const int key_ = kb_ + jj_;                                  \
                if (!((key_ < qr_) || (qr_ == 0 && key_ == 0))) sv_ = -1.0e30f; \
            }                                                                \
            pv_[jj_] = __builtin_amdgcn_exp2f(sv_);                          \
            la_ += pv_[jj_];                                                 \
        }                                                                    \
        l[ng_] += la_;                                                       \
        union { unsigned u[4]; bf16x8 v; } pf_;                              \
        pf_.u[0] = pk2(pv_[0], pv_[1]);                                      \
        pf_.u[1] = pk2(pv_[2], pv_[3]);                                      \
        pf_.u[2] = pk2(pv_[4], pv_[5]);                                      \
        pf_.u[3] = pk2(pv_[6], pv_[7]);                                      \
        o[0][ng_] = __builtin_amdgcn_mfma_f32_16x16x32_bf16(vb0_, pf_.v, o[0][ng_], 0, 0, 0); \
        o[1][ng_] = __builtin_amdgcn_mfma_f32_16x16x32_bf16(vb1_, pf_.v, o[1][ng_], 0, 0, 0); \
        o[2][ng_] = __builtin_amdgcn_mfma_f32_16x16x32_bf16(vb2_, pf_.v, o[2][ng_], 0, 0, 0); \
        o[3][ng_] = __builtin_amdgcn_mfma_f32_16x16x32_bf16(vb3_, pf_.v, o[3][ng_], 0, 0, 0); \
    }                                                                        \
} while (0)

__global__ __launch_bounds__(512, 4)
void attn17(const float* __restrict__ Q, const float* __restrict__ beta,
            const unsigned short* __restrict__ F, float* __restrict__ out)
{
    __shared__ float slab[2][64][72];   // [kh][row][0..63: O, 64: l]
    __shared__ float bl[S_];            // exp-scaled beta (log2 domain)

    const int bid = blockIdx.x;
    const int hd = bid & 15;            // head pinned to XCD bid&7 (2 heads/XCD)
    const int rest = bid >> 4;          // 0..31
    // odd/even map: co-resident pair (bid, bid+256) gets j1+j2 = 31 (33 tiles)
    const int j = (rest < 16) ? (31 - 2 * rest) : (2 * (rest - 16));

    const int q0 = j << 6;
    const int nt = j + 1;

    const float* Qh = Q + (size_t)hd * S_ * D_;
    const unsigned short* Fh = F + (size_t)hd * 32 * 8192;

    const int t = threadIdx.x, lane = t & 63;
    const int wv = t >> 6;
    const int kh = wv & 1, par = (wv >> 1) & 1, qh = wv >> 2;
    const int n_l = lane & 15, qd = lane >> 4;
    const int qbase = q0 + (qh << 5);

    // ---- stage beta*log2e in LDS once (broadcast reads thereafter) ----
    #pragma unroll
    for (int i = 0; i < 4; ++i) bl[t + i * 512] = beta[t + i * 512] * LOG2E;
    __syncthreads();

    // fragment offsets (ushort) within one tile's 8192-ushort block
    const int lo = lane * 8;
    int kfo[2][2], vfo[4];
    #pragma unroll
    for (int mb = 0; mb < 2; ++mb)
        #pragma unroll
        for (int hh = 0; hh < 2; ++hh)
            kfo[mb][hh] = ((kh << 2) | (mb << 1) | hh) * 512 + lo;
    #pragma unroll
    for (int mb = 0; mb < 4; ++mb)
        vfo[mb] = (8 + (kh << 2) + mb) * 512 + lo;

    const int kvo = (kh << 5) + (qd << 3);   // lane's key offset within a tile

    // ---- Qeff B-fragments from global fp32 Q (two q-rows per lane) ----
    bf16x8 qb[2][2];
    #pragma unroll
    for (int ng = 0; ng < 2; ++ng) {
        const int q = qbase + (ng << 4) + n_l;
        const float wp = (q > 0) ? 0.7f : 0.0f;
        const float wn = (q + 1 < S_) ? 0.7f : 0.0f;
        const float* qc = Qh + (size_t)q * D_;
        const float* qpp = qc - ((q > 0) ? D_ : 0);
        const float* qnn = qc + ((q + 1 < S_) ? D_ : 0);
        #pragma unroll
        for (int hh = 0; hh < 2; ++hh) {
            const int d0 = (hh << 5) + (qd << 3);
            float4 c0 = *(const float4*)(qc + d0),  c1 = *(const float4*)(qc + d0 + 4);
            float4 p0 = *(const float4*)(qpp + d0), p1 = *(const float4*)(qpp + d0 + 4);
            float4 n0 = *(const float4*)(qnn + d0), n1 = *(const float4*)(qnn + d0 + 4);
            float e0 = fmaf(wn, n0.x, fmaf(wp, p0.x, c0.x));
            float e1 = fmaf(wn, n0.y, fmaf(wp, p0.y, c0.y));
            float e2 = fmaf(wn, n0.z, fmaf(wp, p0.z, c0.z));
            float e3 = fmaf(wn, n0.w, fmaf(wp, p0.w, c0.w));
            float e4 = fmaf(wn, n1.x, fmaf(wp, p1.x, c1.x));
            float e5 = fmaf(wn, n1.y, fmaf(wp, p1.y, c1.y));
            float e6 = fmaf(wn, n1.z, fmaf(wp, p1.z, c1.z));
            float e7 = fmaf(wn, n1.w, fmaf(wp, p1.w, c1.w));
            union { unsigned u[4]; bf16x8 v; } qu;
            qu.u[0] = pk2(e0, e1); qu.u[1] = pk2(e2, e3);
            qu.u[2] = pk2(e4, e5); qu.u[3] = pk2(e6, e7);
            qb[ng][hh] = qu.v;
        }
    }

    f32x4 o[4][2];
    float l[2] = {0.0f, 0.0f};
    #pragma unroll
    for (int mb = 0; mb < 4; ++mb)
        #pragma unroll
        for (int ng = 0; ng < 2; ++ng) o[mb][ng] = (f32x4){0, 0, 0, 0};

    // ---- barrier-free K-loop: single ka buffer, in-comp prefetch (+2) ----
    bf16x8 ka[2][2];
    int it = par;
    if (it < nt) {
        LD_KA(it, ka);
        for (; it + 2 < nt; it += 2) {
            COMP_T(it, ka, LD_KA(it + 2, ka));
        }
        COMP_T(it, ka, (void)0);
    }

    // ---- epilogue: quad-reduce l, 3-barrier 4-way (kh x par) combine ----
    #pragma unroll
    for (int ng = 0; ng < 2; ++ng) {
        l[ng] += __shfl_xor(l[ng], 16);
        l[ng] += __shfl_xor(l[ng], 32);
    }
    if (par == 1) {
        #pragma unroll
        for (int ng = 0; ng < 2; ++ng) {
            const int row = (qh << 5) + (ng << 4) + n_l;
            #pragma unroll
            for (int mb = 0; mb < 4; ++mb)
                *(float4*)&slab[kh][row][(mb << 4) + (qd << 2)] =
                    make_float4(o[mb][ng][0], o[mb][ng][1], o[mb][ng][2], o[mb][ng][3]);
            if (qd == 0) slab[kh][row][64] = l[ng];
        }
    }
    __syncthreads();
    if (par == 0) {
        #pragma unroll
        for (int ng = 0; ng < 2; ++ng) {
            const int row = (qh << 5) + (ng << 4) + n_l;
            #pragma unroll
            for (int mb = 0; mb < 4; ++mb) {
                float4 pv4 = *(float4*)&slab[kh][row][(mb << 4) + (qd << 2)];
                o[mb][ng][0] += pv4.x; o[mb][ng][1] += pv4.y;
                o[mb][ng][2] += pv4.z; o[mb][ng][3] += pv4.w;
            }
            l[ng] += slab[kh][row][64];
            if (kh == 0) {   // publish kh0 totals (same wave read-then-write, in order)
                #pragma unroll
                for (int mb = 0; mb < 4; ++mb)
                    *(float4*)&slab[0][row][(mb << 4) + (qd << 2)] =
                        make_float4(o[mb][ng][0], o[mb][ng][1], o[mb][ng][2], o[mb][ng][3]);
                if (qd == 0) slab[0][row][64] = l[ng];
            }
        }
    }
    __syncthreads();
    if (par == 0 && kh == 1) {
        #pragma unroll
        for (int ng = 0; ng < 2; ++ng) {
            const int row = (qh << 5) + (ng << 4) + n_l;
            const float inv = 1.0f / (l[ng] + slab[0][row][64]);
            float* op = out + ((size_t)hd * S_ + q0 + row) * D_ + (qd << 2);
            #pragma unroll
            for (int mb = 0; mb < 4; ++mb) {
                float4 pv4 = *(float4*)&slab[0][row][(mb << 4) + (qd << 2)];
                *(float4*)(op + (mb << 4)) =
                    make_float4((o[mb][ng][0] + pv4.x) * inv, (o[mb][ng][1] + pv4.y) * inv,
                                (o[mb][ng][2] + pv4.z) * inv, (o[mb][ng][3] + pv4.w) * inv);
            }
        }
    }
}

#undef LD_KA
#undef COMP_T

extern "C" void kernel_launch(void* const* d_in, const int* in_sizes, int n_in,
                              void* d_out, int out_size, void* d_ws, size_t ws_size,
                              hipStream_t stream) {
    const float* Q    = (const float*)d_in[0];
    const float* K    = (const float*)d_in[1];
    const float* V    = (const float*)d_in[2];
    const float* beta = (const float*)d_in[3];
    // d_in[4]: causal mask (deterministic triu) — handled analytically in-kernel.
    float* out = (float*)d_out;

    unsigned short* F = (unsigned short*)d_ws;   // 16 hd x 32 t x 16 frag x 512 = 8 MB

    cvt8<<<dim3(512), 256, 0, stream>>>(K, V, F);
    attn17<<<dim3(512), 512, 0, stream>>>(Q, beta, F, out);
}